// Round 3
// baseline (1291.113 us; speedup 1.0000x reference)
//
#include <hip/hip_runtime.h>
#include <hip/hip_cooperative_groups.h>

namespace cg = cooperative_groups;

#define NN 100000
#define LL 1024
#define HH 512
#define DD 256
#define TOPK 64
#define CAP 3072
#define DELTA 3e-3f

// ---- workspace layout (bytes) ----
#define WS_W1T   0u            // ushort[512*1024]  (fragment-major W1F)
#define WS_B2    1048576u      // ushort[512*512]   (fragment-major B2F)
#define WS_Z     1572864u      // zeroed region start
#define Z_MNUM   0u            // float[512]
#define Z_SEXP   2048u         // float
#define Z_LOSS   2052u         // float
#define Z_CNTT   2056u         // uint
#define Z_CNTB   2060u         // uint
#define Z_HIST   2064u         // uint[2048]
#define Z_WSA    10256u        // float[100032] (A accumulators, padded)
#define Z_PARAMS 410384u       // uint[8]: [0]=thrT [1]=thrB [2]=binT [3]=binB [4]=remT [5]=remB
#define Z_SEL    410416u       // uint[128]
#define Z_CANDT  410928u       // uint[3072]  (doubles as hist2T before collect)
#define Z_CANDB  423216u       // uint[3072]  (doubles as hist2B before collect)
#define Z_AEXT   435504u       // float[3072]
#define Z_AEXB   447792u       // float[3072]
#define Z_ZWORDS 108876        // words zeroed each launch (bytes [0, 435504))

typedef float  f32x16 __attribute__((ext_vector_type(16)));
typedef short  bf16x8 __attribute__((ext_vector_type(8)));

#define MFMA(a,b,c) __builtin_amdgcn_mfma_f32_32x32x16_bf16(a,b,c,0,0,0)

__device__ __forceinline__ unsigned short f2bf(float x){
  unsigned u = __float_as_uint(x);
  u += 0x7FFFu + ((u >> 16) & 1u);          // round-to-nearest-even
  return (unsigned short)(u >> 16);
}
__device__ __forceinline__ float bf2f(unsigned short v){
  return __uint_as_float(((unsigned)v) << 16);
}
__device__ __forceinline__ unsigned sortable_u(float f){
  unsigned u = __float_as_uint(f);
  return (u & 0x80000000u) ? ~u : (u | 0x80000000u);
}
__device__ __forceinline__ float inv_sortable(unsigned u){
  unsigned orig = (u & 0x80000000u) ? (u ^ 0x80000000u) : ~u;
  return __uint_as_float(orig);
}
// packed f32->bf16 RNE (same rounding as f2bf)
__device__ __forceinline__ unsigned cvtpk(float lo, float hi){
  unsigned r;
  asm("v_cvt_pk_bf16_f32 %0, %1, %2" : "=v"(r) : "v"(lo), "v"(hi));
  return r;
}

// ---------------- K0: weight repack to MFMA-fragment-major + zero scratch ----
__global__ __launch_bounds__(256)
void k0_prep(const float* __restrict__ W1, const float* __restrict__ Wa,
             const float* __restrict__ Wb,
             unsigned short* __restrict__ W1F, unsigned short* __restrict__ B2F,
             unsigned* __restrict__ zwords)
{
  __shared__ unsigned short T[16 * 512];
  int b = blockIdx.x, tid = threadIdx.x;
  if (b < 64){
    int s = b;                      // k-slice of 16 rows of W1
    #pragma unroll
    for (int i = 0; i < 8; ++i){
      int g = tid + 256 * i;        // float4 index among 16*128
      int kk = g >> 7, c4 = g & 127;
      float4 v = *(const float4*)(W1 + (size_t)(16 * s + kk) * HH + c4 * 4);
      uint2 pk; pk.x = cvtpk(v.x, v.y); pk.y = cvtpk(v.z, v.w);
      *(uint2*)(T + kk * 512 + c4 * 4) = pk;
    }
    __syncthreads();
    int c = tid >> 4, lbase = (tid & 15) * 4;
    #pragma unroll
    for (int q = 0; q < 4; ++q){
      int l = lbase + q; int l31 = l & 31; int kh = l >> 5;
      unsigned short tmp[8];
      #pragma unroll
      for (int j = 0; j < 8; ++j) tmp[j] = T[(kh * 8 + j) * 512 + c * 32 + l31];
      *(bf16x8*)(W1F + ((size_t)(c * 64 + s) * 64 + l) * 8) = *(bf16x8*)tmp;
    }
  } else if (b < 96){
    int s = b - 64;                 // k-slice of 16 rows of Wa/Wb
    #pragma unroll
    for (int i = 0; i < 4; ++i){
      int g = tid + 256 * i;        // float4 index among 16*64
      int kk = g >> 6, c4 = g & 63;
      float4 va = *(const float4*)(Wa + (size_t)(16 * s + kk) * DD + c4 * 4);
      float4 vb = *(const float4*)(Wb + (size_t)(16 * s + kk) * DD + c4 * 4);
      uint2 pa; pa.x = cvtpk(va.x, va.y); pa.y = cvtpk(va.z, va.w);
      uint2 pb; pb.x = cvtpk(vb.x, vb.y); pb.y = cvtpk(vb.z, vb.w);
      *(uint2*)(T + kk * 512 + c4 * 4) = pa;
      *(uint2*)(T + kk * 512 + 256 + c4 * 4) = pb;
    }
    __syncthreads();
    int c = tid >> 4, lbase = (tid & 15) * 4;
    int col0 = (c & 1) * 256 + (c >> 1) * 32;   // [Wa(0..255)|Wb(256..511)]
    #pragma unroll
    for (int q = 0; q < 4; ++q){
      int l = lbase + q; int l31 = l & 31; int kh = l >> 5;
      unsigned short tmp[8];
      #pragma unroll
      for (int j = 0; j < 8; ++j) tmp[j] = T[(kh * 8 + j) * 512 + col0 + l31];
      *(bf16x8*)(B2F + ((size_t)(c * 32 + s) * 64 + l) * 8) = *(bf16x8*)tmp;
    }
  } else {
    for (int i = (b - 96) * 256 + tid; i < Z_ZWORDS; i += 32 * 256) zwords[i] = 0u;
  }
}

// ---------------- mega kernel: h1 GEMM + attention GEMM + A + M + hist -------
__global__ __launch_bounds__(512, 2)
void k_mega(const float* __restrict__ h, const unsigned short* __restrict__ W1F,
            const unsigned short* __restrict__ B2F,
            const float* __restrict__ b1, const float* __restrict__ ba,
            const float* __restrict__ bbg, const float* __restrict__ Wc,
            const float* __restrict__ bc,
            float* __restrict__ outA,          // d_out + 5  (A_raw)
            float* __restrict__ wsA,           // zeroed accumulators (padded to 100032)
            float* __restrict__ Mnum, float* __restrict__ sum_exp,
            unsigned* __restrict__ histg)
{
  __shared__ __align__(16) unsigned short SM[64 * 512];

  const int tid  = threadIdx.x;
  const int wid  = tid >> 6;
  const int lane = tid & 63;
  const int l31  = lane & 31;
  const int half = lane >> 5;
  const int r0   = blockIdx.x * 64;

  const int scol = tid & 63;
  const int srow = tid >> 6;

  const unsigned short* bp = W1F + (size_t)(2 * wid) * 32768 + (size_t)lane * 8;

  f32x16 acc00 = (f32x16)0.f, acc01 = (f32x16)0.f, acc10 = (f32x16)0.f, acc11 = (f32x16)0.f;

  unsigned short* buf0 = SM;
  unsigned short* buf1 = SM + 64 * 256;

  // ---- prologue: stage chunk 0 ----
  #pragma unroll
  for (int j = 0; j < 8; ++j){
    int r = srow + 8 * j;
    int gr = r0 + r; if (gr > NN - 1) gr = NN - 1;
    float4 v = *(const float4*)(h + (size_t)gr * LL + scol * 4);
    uint2 pk; pk.x = cvtpk(v.x, v.y); pk.y = cvtpk(v.z, v.w);
    *(uint2*)(buf0 + r * 256 + ((((scol >> 1) ^ (r & 31)) << 3) + (scol & 1) * 4)) = pk;
  }
  __syncthreads();

  unsigned short* rb = buf0;
  unsigned short* wb = buf1;

#define SUBIT(i) { \
    const int s0_ = sb + 2 * (i), s1_ = s0_ + 1; \
    bf16x8 b00 = *(const bf16x8*)(bp + s0_ * 512); \
    bf16x8 b01 = *(const bf16x8*)(bp + s1_ * 512); \
    bf16x8 b10 = *(const bf16x8*)(bp + 32768 + s0_ * 512); \
    bf16x8 b11 = *(const bf16x8*)(bp + 32768 + s1_ * 512); \
    const int ck0 = 4 * (i) + half, ck1 = ck0 + 2; \
    bf16x8 a0k0 = *(const bf16x8*)(rb + l31 * 256 + ((ck0 ^ l31) << 3)); \
    bf16x8 a1k0 = *(const bf16x8*)(rb + (32 + l31) * 256 + ((ck0 ^ l31) << 3)); \
    bf16x8 a0k1 = *(const bf16x8*)(rb + l31 * 256 + ((ck1 ^ l31) << 3)); \
    bf16x8 a1k1 = *(const bf16x8*)(rb + (32 + l31) * 256 + ((ck1 ^ l31) << 3)); \
    acc00 = MFMA(a0k0, b00, acc00); acc01 = MFMA(a0k0, b10, acc01); \
    acc10 = MFMA(a1k0, b00, acc10); acc11 = MFMA(a1k0, b10, acc11); \
    acc00 = MFMA(a0k1, b01, acc00); acc01 = MFMA(a0k1, b11, acc01); \
    acc10 = MFMA(a1k1, b01, acc10); acc11 = MFMA(a1k1, b11, acc11); }

#define LDH(dst, j) { \
    int r_ = srow + 8 * (j); \
    int gr_ = r0 + r_; if (gr_ > NN - 1) gr_ = NN - 1; \
    dst = *(const float4*)(h + (size_t)gr_ * LL + coff + scol * 4); }

#define WRH(v, j) { \
    int r_ = srow + 8 * (j); \
    uint2 pk_; pk_.x = cvtpk((v).x, (v).y); pk_.y = cvtpk((v).z, (v).w); \
    *(uint2*)(wb + r_ * 256 + ((((scol >> 1) ^ (r_ & 31)) << 3) + (scol & 1) * 4)) = pk_; }

  #pragma unroll 1
  for (int ch = 0; ch < 4; ++ch){
    const int sb = ch * 16;
    const int coff = (ch + 1) * 256;     // next chunk's float column base
    const bool st = (ch < 3);
    float4 hA, hB;
    if (st){ LDH(hA, 0) LDH(hB, 1) }
    SUBIT(0) SUBIT(1)
    if (st){ WRH(hA, 0) WRH(hB, 1) LDH(hA, 2) LDH(hB, 3) }
    SUBIT(2) SUBIT(3)
    if (st){ WRH(hA, 2) WRH(hB, 3) LDH(hA, 4) LDH(hB, 5) }
    SUBIT(4) SUBIT(5)
    if (st){ WRH(hA, 4) WRH(hB, 5) LDH(hA, 6) LDH(hB, 7) }
    SUBIT(6) SUBIT(7)
    if (st){ WRH(hA, 6) WRH(hB, 7) }
    __syncthreads();
    { unsigned short* t = rb; rb = wb; wb = t; }
  }

  // epilogue1: bias + relu + bf16, write swizzled h1 [64][512] to LDS
  {
    float b1v0 = b1[wid * 64 + l31];
    float b1v1 = b1[wid * 64 + 32 + l31];
    int cb0 = wid * 8 + (l31 >> 3);
    int cb1 = wid * 8 + 4 + (l31 >> 3);
    int wi = l31 & 7;
    #pragma unroll
    for (int reg = 0; reg < 16; ++reg){
      int rA = (reg & 3) + ((reg >> 2) << 3) + (half << 2);
      int rB = rA + 32;
      float v;
      v = fmaxf(acc00[reg] + b1v0, 0.f); SM[rA * 512 + ((cb0 ^ (rA & 7)) << 3) + wi] = f2bf(v);
      v = fmaxf(acc01[reg] + b1v1, 0.f); SM[rA * 512 + ((cb1 ^ (rA & 7)) << 3) + wi] = f2bf(v);
      v = fmaxf(acc10[reg] + b1v0, 0.f); SM[rB * 512 + ((cb0 ^ (rB & 7)) << 3) + wi] = f2bf(v);
      v = fmaxf(acc11[reg] + b1v1, 0.f); SM[rB * 512 + ((cb1 ^ (rB & 7)) << 3) + wi] = f2bf(v);
    }
  }
  __syncthreads();

  // GEMM2: pre_a / pre_b = h1 @ [Wa|Wb]
  f32x16 q00 = (f32x16)0.f, q01 = (f32x16)0.f, q10 = (f32x16)0.f, q11 = (f32x16)0.f;
  const unsigned short* p2 = B2F + (size_t)(2 * wid) * 16384 + (size_t)lane * 8;
  const int m0x = l31 & 7;
  #pragma unroll 1
  for (int kc = 0; kc < 16; ++kc){
    #pragma unroll
    for (int ks = 0; ks < 2; ++ks){
      int s = kc * 2 + ks;
      bf16x8 b0 = *(const bf16x8*)(p2 + s * 512);
      bf16x8 b1 = *(const bf16x8*)(p2 + 16384 + s * 512);
      int sw = (((kc * 4 + ks * 2 + half) ^ m0x) << 3);
      bf16x8 a0 = *(const bf16x8*)(SM + l31 * 512 + sw);
      bf16x8 a1 = *(const bf16x8*)(SM + (32 + l31) * 512 + sw);
      q00 = MFMA(a0, b0, q00); q01 = MFMA(a0, b1, q01);
      q10 = MFMA(a1, b0, q10); q11 = MFMA(a1, b1, q11);
    }
  }

  // epilogue2: A_row partials -> global atomics
  {
    int ca = wid * 32 + l31;
    float bav = ba[ca], bbv = bbg[ca], wcv = Wc[ca];
    #pragma unroll
    for (int mt = 0; mt < 2; ++mt){
      #pragma unroll
      for (int reg = 0; reg < 16; ++reg){
        float pav = (mt ? q10[reg] : q00[reg]) + bav;
        float pbv = (mt ? q11[reg] : q01[reg]) + bbv;
        float p = tanhf(pav) * (1.f / (1.f + expf(-pbv))) * wcv;
        p += __shfl_xor(p, 1, 64);  p += __shfl_xor(p, 2, 64);
        p += __shfl_xor(p, 4, 64);  p += __shfl_xor(p, 8, 64);
        p += __shfl_xor(p, 16, 64);
        if (l31 == 0){
          int rl = mt * 32 + (reg & 3) + ((reg >> 2) << 3) + (half << 2);
          atomicAdd(&wsA[r0 + rl], p);
        }
      }
    }
  }
  __syncthreads();
  if (tid < 64){
    int g = r0 + tid;
    if (g < NN){
      float Ar = atomicAdd(&wsA[g], 0.0f) + bc[0];   // atomic read (L2)
      outA[g] = Ar;
      atomicAdd(&histg[sortable_u(Ar) >> 21], 1u);   // fused level-1 histogram
    }
  }
  __syncthreads();

  // M partials: pm[col] = sum_r exp(A_r) * h1[r][col]
  float ev = 0.f;
  { int g = r0 + lane; if (g < NN) ev = expf(outA[g]); }
  float pm = 0.f;
  const int tch = tid >> 3, twi = tid & 7;
  #pragma unroll 4
  for (int r = 0; r < 64; ++r){
    float e = __shfl(ev, r, 64);
    pm += e * bf2f(SM[r * 512 + ((tch ^ (r & 7)) << 3) + twi]);
  }
  atomicAdd(&Mnum[tid], pm);
  if (wid == 0){
    float s = ev;
    s += __shfl_xor(s, 1, 64);  s += __shfl_xor(s, 2, 64);  s += __shfl_xor(s, 4, 64);
    s += __shfl_xor(s, 8, 64);  s += __shfl_xor(s, 16, 64); s += __shfl_xor(s, 32, 64);
    if (lane == 0) atomicAdd(sum_exp, s);
  }
}

// ---------------- cooperative tail: scan->hist2->scan2->collect->exact->select->inst->final
struct CoopArgs {
  const float* h; const float* W1; const float* b1;
  const float* Wa; const float* ba; const float* Wb; const float* bbg;
  const float* Wc; const float* bc;
  const float* Winst; const float* binst; const float* Wcls; const float* bcls;
  const int* label;
  float* out; float* A;
  unsigned* hist; unsigned* params; unsigned* h2T; unsigned* h2B;
  unsigned* cntT; unsigned* cntB; unsigned* candT; unsigned* candB;
  float* AexT; float* AexB; unsigned* sel;
  float* Mnum; float* sexp; float* lsum;
};

#define CGRID 256

__global__ __launch_bounds__(256, 1)
void k_coop(CoopArgs a)
{
  cg::grid_group grid = cg::this_grid();
  const int tid = threadIdx.x;
  const int bid = blockIdx.x;
  __shared__ __align__(16) char SMEM[24640];

  // ---- P0: level-1 scan (block 0) ----
  if (bid == 0){
    unsigned* lh = (unsigned*)SMEM;
    for (int i = tid; i < 2048; i += 256) lh[i] = a.hist[i];
    __syncthreads();
    if (tid == 0){
      unsigned c = 0, hh = 0; int b = 2047;
      for (; b >= 0; --b){ hh = lh[b]; c += hh; if (c >= TOPK) break; }
      if (b < 0) b = 0;
      a.params[2] = (unsigned)b; a.params[4] = TOPK - (c - hh);
      c = 0; hh = 0; int b2 = 0;
      for (; b2 < 2048; ++b2){ hh = lh[b2]; c += hh; if (c >= TOPK) break; }
      if (b2 > 2047) b2 = 2047;
      a.params[3] = (unsigned)b2; a.params[5] = TOPK - (c - hh);
    }
  }
  grid.sync();

  // ---- P1: level-2 histogram ----
  {
    unsigned* lh = (unsigned*)SMEM;               // 4096 uints
    for (int i = tid; i < 4096; i += 256) lh[i] = 0u;
    __syncthreads();
    unsigned bT = a.params[2], bB = a.params[3];
    for (int i = bid * 256 + tid; i < NN; i += CGRID * 256){
      unsigned u = sortable_u(a.A[i]);
      unsigned b = u >> 21;
      if (b == bT) atomicAdd(&lh[(u >> 10) & 2047u], 1u);
      if (b == bB) atomicAdd(&lh[2048 + ((u >> 10) & 2047u)], 1u);
    }
    __syncthreads();
    for (int i = tid; i < 2048; i += 256){
      if (lh[i])        atomicAdd(&a.h2T[i], lh[i]);
      if (lh[2048 + i]) atomicAdd(&a.h2B[i], lh[2048 + i]);
    }
  }
  grid.sync();

  // ---- P2: level-2 scan (block 0) ----
  if (bid == 0){
    unsigned* lh = (unsigned*)SMEM;               // [0..2047]=h2T [2048..4095]=h2B
    for (int i = tid; i < 2048; i += 256){ lh[i] = a.h2T[i]; lh[2048 + i] = a.h2B[i]; }
    __syncthreads();
    if (tid < 128){
      int side = tid >> 6;
      int lane = tid & 63;
      const unsigned* h2 = lh + side * 2048;
      unsigned bT  = a.params[2 + side];
      unsigned rem = a.params[4 + side];
      unsigned cs = 0;
      int base = lane * 32;
      #pragma unroll 4
      for (int j = 0; j < 32; ++j) cs += h2[base + j];
      unsigned before = 0;
      for (int j = 0; j < 64; ++j){
        unsigned v = __shfl(cs, j, 64);
        bool earlier = side ? (j < lane) : (j > lane);
        if (earlier) before += v;
      }
      if (before < rem && before + cs >= rem){
        unsigned c = before; int s = base;
        if (side == 0){
          for (int b = base + 31; b >= base; --b){ c += h2[b]; if (c >= rem){ s = b; break; } }
          unsigned ulo = (bT << 21) | ((unsigned)s << 10);
          float v = inv_sortable(ulo) - DELTA;
          a.params[0] = sortable_u(v);
        } else {
          for (int b = base; b < base + 32; ++b){ c += h2[b]; if (c >= rem){ s = b; break; } }
          unsigned uhi = (bT << 21) | ((unsigned)s << 10) | 1023u;
          float v = inv_sortable(uhi) + DELTA;
          a.params[1] = sortable_u(v);
        }
      }
    }
  }
  grid.sync();

  // ---- P3: collect candidates ----
  {
    unsigned p0 = a.params[0], p1 = a.params[1];
    for (int i = bid * 256 + tid; i < NN; i += CGRID * 256){
      unsigned u = sortable_u(a.A[i]);
      if (u >= p0){ unsigned pos = atomicAdd(a.cntT, 1u); if (pos < CAP) a.candT[pos] = (unsigned)i; }
      if (u <= p1){ unsigned pos = atomicAdd(a.cntB, 1u); if (pos < CAP) a.candB[pos] = (unsigned)i; }
    }
  }
  grid.sync();

  // ---- P4: exact A for candidates (1 row per block) ----
  {
    unsigned cT = *a.cntT; if (cT > CAP) cT = CAP;
    unsigned cB = *a.cntB; if (cB > CAP) cB = CAP;
    int tot = (int)(cT + cB);
    float* hrow  = (float*)SMEM;                  // 1024 f
    float* h1row = (float*)(SMEM + 4096);         // 512 f
    float* red   = (float*)(SMEM + 6144);         // 4 f
    for (int r = bid; r < tot; r += CGRID){
      int side = (r >= (int)cT);
      int j = side ? r - (int)cT : r;
      unsigned row = side ? a.candB[j] : a.candT[j];
      __syncthreads();
      ((float4*)hrow)[tid] = ((const float4*)(a.h + (size_t)row * LL))[tid];
      __syncthreads();
      float s0 = a.b1[tid], s1 = a.b1[tid + 256];
      for (int k = 0; k < LL; ++k){
        float hv = hrow[k];
        s0 += hv * a.W1[k * HH + tid];
        s1 += hv * a.W1[k * HH + tid + 256];
      }
      h1row[tid] = fmaxf(s0, 0.f); h1row[tid + 256] = fmaxf(s1, 0.f);
      __syncthreads();
      float pa = a.ba[tid], pb = a.bbg[tid];
      for (int k = 0; k < HH; ++k){
        float hv = h1row[k];
        pa += hv * a.Wa[k * DD + tid];
        pb += hv * a.Wb[k * DD + tid];
      }
      float p = tanhf(pa) * (1.f / (1.f + expf(-pb))) * a.Wc[tid];
      p += __shfl_xor(p, 1, 64);  p += __shfl_xor(p, 2, 64);  p += __shfl_xor(p, 4, 64);
      p += __shfl_xor(p, 8, 64);  p += __shfl_xor(p, 16, 64); p += __shfl_xor(p, 32, 64);
      if ((tid & 63) == 0) red[tid >> 6] = p;
      __syncthreads();
      if (tid == 0)
        (side ? a.AexB : a.AexT)[j] = red[0] + red[1] + red[2] + red[3] + a.bc[0];
    }
  }
  grid.sync();

  // ---- P5: select top-64 each side (block 0) ----
  if (bid == 0){
    unsigned long long* keys = (unsigned long long*)SMEM;        // CAP entries (24KB)
    unsigned long long* wmax = (unsigned long long*)(SMEM + 24576);
    __shared__ unsigned long long best_s;
    for (int side = 0; side < 2; ++side){
      unsigned cnt = side ? *a.cntB : *a.cntT; if (cnt > CAP) cnt = CAP;
      const unsigned* cand = side ? a.candB : a.candT;
      const float* Aex = side ? a.AexB : a.AexT;
      for (int j = tid; j < (int)cnt; j += 256){
        unsigned su = sortable_u(Aex[j]);
        if (side) su = ~su;
        keys[j] = (((unsigned long long)su) << 32) | (unsigned long long)(0xFFFFFFFFu - cand[j]);
      }
      __syncthreads();
      for (int it = 0; it < TOPK; ++it){
        unsigned long long loc = 0ull;
        for (int j = tid; j < (int)cnt; j += 256){ unsigned long long k = keys[j]; loc = (k > loc) ? k : loc; }
        for (int off = 1; off < 64; off <<= 1){
          unsigned long long o = __shfl_xor(loc, off, 64);
          loc = (o > loc) ? o : loc;
        }
        if ((tid & 63) == 0) wmax[tid >> 6] = loc;
        __syncthreads();
        if (tid == 0){
          unsigned long long m01 = (wmax[0] > wmax[1]) ? wmax[0] : wmax[1];
          unsigned long long m23 = (wmax[2] > wmax[3]) ? wmax[2] : wmax[3];
          unsigned long long bb_ = (m01 > m23) ? m01 : m23;
          best_s = bb_;
          a.sel[side * TOPK + it] = 0xFFFFFFFFu - (unsigned)(bb_ & 0xFFFFFFFFull);
        }
        __syncthreads();
        unsigned long long bv = best_s;
        for (int j = tid; j < (int)cnt; j += 256) if (keys[j] == bv) keys[j] = 0ull;
        __syncthreads();
      }
      __syncthreads();
    }
  }
  grid.sync();

  // ---- P6: instance classifier (blocks 0..127) ----
  if (bid < 128){
    float* hrow  = (float*)SMEM;                  // 1024 f
    float* h1row = (float*)(SMEM + 4096);         // 512 f
    float* red   = (float*)(SMEM + 6144);         // [4][2] f
    unsigned row = a.sel[bid];
    ((float4*)hrow)[tid] = ((const float4*)(a.h + (size_t)row * LL))[tid];
    __syncthreads();
    float s0 = a.b1[tid], s1 = a.b1[tid + 256];
    for (int k = 0; k < LL; ++k){
      float hv = hrow[k];
      s0 += hv * a.W1[k * HH + tid];
      s1 += hv * a.W1[k * HH + tid + 256];
    }
    h1row[tid] = fmaxf(s0, 0.f); h1row[tid + 256] = fmaxf(s1, 0.f);
    __syncthreads();
    float l0 = 0.f, l1 = 0.f;
    for (int d = tid; d < HH; d += 256){
      float hv = h1row[d];
      l0 += hv * a.Winst[d * 2];
      l1 += hv * a.Winst[d * 2 + 1];
    }
    for (int off = 1; off < 64; off <<= 1){ l0 += __shfl_xor(l0, off, 64); l1 += __shfl_xor(l1, off, 64); }
    if ((tid & 63) == 0){ red[(tid >> 6) * 2] = l0; red[(tid >> 6) * 2 + 1] = l1; }
    __syncthreads();
    if (tid == 0){
      float L0 = red[0] + red[2] + red[4] + red[6] + a.binst[0];
      float L1 = red[1] + red[3] + red[5] + red[7] + a.binst[1];
      int lab = a.label[0];
      int tgt = (bid < TOPK) ? lab : 0;
      a.out[100006 + bid] = (L1 > L0) ? 1.f : 0.f;
      a.out[100134 + bid] = (float)tgt;
      float m = fmaxf(L0, L1);
      float lse = m + logf(expf(L0 - m) + expf(L1 - m));
      float lp = ((tgt == 1) ? L1 : L0) - lse;
      atomicAdd(a.lsum, -lp);
    }
  }
  grid.sync();

  // ---- P7: bag head (block 0) ----
  if (bid == 0){
    float* red = (float*)SMEM;                    // [4][2]
    float S = *a.sexp;
    float p0 = 0.f, p1 = 0.f;
    for (int c = tid; c < HH; c += 256){
      float m = a.Mnum[c] / S;
      p0 += m * a.Wcls[c * 2];
      p1 += m * a.Wcls[c * 2 + 1];
    }
    for (int off = 1; off < 64; off <<= 1){ p0 += __shfl_xor(p0, off, 64); p1 += __shfl_xor(p1, off, 64); }
    if ((tid & 63) == 0){ red[(tid >> 6) * 2] = p0; red[(tid >> 6) * 2 + 1] = p1; }
    __syncthreads();
    if (tid == 0){
      float L0 = a.bcls[0] + red[0] + red[2] + red[4] + red[6];
      float L1 = a.bcls[1] + red[1] + red[3] + red[5] + red[7];
      a.out[0] = L0; a.out[1] = L1;
      float mm = fmaxf(L0, L1);
      float e0 = expf(L0 - mm), e1 = expf(L1 - mm);
      a.out[2] = e0 / (e0 + e1); a.out[3] = e1 / (e0 + e1);
      a.out[4] = (L1 > L0) ? 1.f : 0.f;
      a.out[100005] = atomicAdd(a.lsum, 0.0f) / 128.f;
    }
  }
}

extern "C" void kernel_launch(void* const* d_in, const int* in_sizes, int n_in,
                              void* d_out, int out_size, void* d_ws, size_t ws_size,
                              hipStream_t stream)
{
  const float* h     = (const float*)d_in[0];
  const float* W1    = (const float*)d_in[1];
  const float* b1    = (const float*)d_in[2];
  const float* Wa    = (const float*)d_in[3];
  const float* ba    = (const float*)d_in[4];
  const float* Wb    = (const float*)d_in[5];
  const float* bbg   = (const float*)d_in[6];
  const float* Wc    = (const float*)d_in[7];
  const float* bc    = (const float*)d_in[8];
  const float* Winst = (const float*)d_in[9];
  const float* binst = (const float*)d_in[10];
  const float* Wcls  = (const float*)d_in[11];
  const float* bcls  = (const float*)d_in[12];
  const int*   label = (const int*)d_in[13];
  float* out = (float*)d_out;

  char* ws = (char*)d_ws;
  unsigned short* W1F = (unsigned short*)(ws + WS_W1T);
  unsigned short* B2F = (unsigned short*)(ws + WS_B2);
  char* Z = ws + WS_Z;
  float*    Mnum   = (float*)(Z + Z_MNUM);
  float*    sexp   = (float*)(Z + Z_SEXP);
  float*    lsum   = (float*)(Z + Z_LOSS);
  unsigned* cntT   = (unsigned*)(Z + Z_CNTT);
  unsigned* cntB   = (unsigned*)(Z + Z_CNTB);
  unsigned* hist   = (unsigned*)(Z + Z_HIST);
  float*    wsA    = (float*)(Z + Z_WSA);
  unsigned* params = (unsigned*)(Z + Z_PARAMS);
  unsigned* sel    = (unsigned*)(Z + Z_SEL);
  unsigned* candT  = (unsigned*)(Z + Z_CANDT);
  unsigned* candB  = (unsigned*)(Z + Z_CANDB);
  float*    AexT   = (float*)(Z + Z_AEXT);
  float*    AexB   = (float*)(Z + Z_AEXB);
  unsigned* h2T    = (unsigned*)(Z + Z_CANDT);   // aliases candT (consumed before collect)
  unsigned* h2B    = (unsigned*)(Z + Z_CANDB);   // aliases candB

  k0_prep<<<128, 256, 0, stream>>>(W1, Wa, Wb, W1F, B2F, (unsigned*)Z);
  k_mega<<<1563, 512, 0, stream>>>(h, W1F, B2F, b1, ba, bbg, Wc, bc,
                                   out + 5, wsA, Mnum, sexp, hist);

  CoopArgs ca;
  ca.h = h; ca.W1 = W1; ca.b1 = b1; ca.Wa = Wa; ca.ba = ba; ca.Wb = Wb; ca.bbg = bbg;
  ca.Wc = Wc; ca.bc = bc; ca.Winst = Winst; ca.binst = binst; ca.Wcls = Wcls; ca.bcls = bcls;
  ca.label = label; ca.out = out; ca.A = out + 5;
  ca.hist = hist; ca.params = params; ca.h2T = h2T; ca.h2B = h2B;
  ca.cntT = cntT; ca.cntB = cntB; ca.candT = candT; ca.candB = candB;
  ca.AexT = AexT; ca.AexB = AexB; ca.sel = sel;
  ca.Mnum = Mnum; ca.sexp = sexp; ca.lsum = lsum;
  void* kargs[] = { (void*)&ca };
  hipLaunchCooperativeKernel(k_coop, dim3(CGRID), dim3(256), kargs, 0, stream);
}